// Round 15
// baseline (262.138 us; speedup 1.0000x reference)
//
#include <hip/hip_runtime.h>
#include <hip/hip_bf16.h>

// ---------------- problem constants (fixed by setup_inputs) ----------------
constexpr int B_  = 8;
constexpr int H_  = 64;
constexpr int W_  = 64;
constexpr int C_  = 192;
constexpr int Dn  = 192;
constexpr int Nst = 8;    // state dim N
constexpr int R_  = 12;
constexpr int K_  = 4;    // directions
constexpr int L_  = H_ * W_;          // 4096
constexpr int CS  = 32;               // scan chunk size
constexpr int GS  = 8;                // pipeline group size (CS % GS == 0)
constexpr int NC  = L_ / CS;          // 128 chunks
constexpr int CPROJ = R_ + 2 * Nst;   // 28
constexpr int MROWS = B_ * L_;        // 32768

typedef __attribute__((ext_vector_type(8))) short short8v;
typedef __attribute__((ext_vector_type(4))) float f32x4;
typedef __attribute__((ext_vector_type(2))) float f32x2;

// t -> spatial position for direction k (verified round 0).
// Within a chunk: lm = map_t(k,t0) + ts*stride (no wrap since CS | 64).
__device__ __forceinline__ int map_t(int k, int t) {
    int tt = (k >= 2) ? (L_ - 1 - t) : t;
    if (k & 1) tt = (tt & 63) * 64 + (tt >> 6);
    return tt;
}

__device__ __forceinline__ short f2bf(float f) {   // round-to-nearest-even
    unsigned u = __float_as_uint(f);
    u += 0x7FFFu + ((u >> 16) & 1u);
    return (short)(u >> 16);
}
__device__ __forceinline__ float bf2f(short s) {
    return __uint_as_float(((unsigned)(unsigned short)s) << 16);
}

// packed fp32 helpers (v_pk_fma_f32 / v_pk_mul_f32 on gfx950)
__device__ __forceinline__ f32x2 mk2(float a, float b) { f32x2 v; v.x = a; v.y = b; return v; }
__device__ __forceinline__ f32x2 lo2(float4 v) { return mk2(v.x, v.y); }
__device__ __forceinline__ f32x2 hi2(float4 v) { return mk2(v.z, v.w); }
__device__ __forceinline__ f32x2 pkfma(f32x2 a, f32x2 b, f32x2 c) {
    return __builtin_elementwise_fma(a, b, c);
}

// ---------------- fused f32 -> bf16 convert (x and all weights) -------------
constexpr int WOFF_IN  = 0;               // w_in  (384x192)
constexpr int WOFF_XP  = 73728;           // xpw   (112x192)
constexpr int WOFF_OUT = 95232;           // wout  (192x192)
constexpr int WTOTAL   = 132096;
constexpr int XUNITS   = MROWS * Dn / 8;  // 786432
constexpr int WUNITS   = WTOTAL / 8;      // 16512
__global__ __launch_bounds__(256) void k_cvt(const float* __restrict__ x,
                                             const float* __restrict__ w_in,
                                             const float* __restrict__ xpw,
                                             const float* __restrict__ wout,
                                             short* __restrict__ x_bf,
                                             short* __restrict__ w_bf) {
    int g = blockIdx.x * 256 + threadIdx.x;
    const float* src;
    short* dst;
    int off;
    if (g < XUNITS) { src = x; dst = x_bf; off = g * 8; }
    else {
        g -= XUNITS;
        if (g >= WUNITS) return;
        int base = g * 8;
        dst = w_bf; off = base;
        if (base < WOFF_XP)       { src = w_in; }
        else if (base < WOFF_OUT) { src = xpw;  src -= WOFF_XP; }
        else                      { src = wout; src -= WOFF_OUT; }
    }
    float4 a = *reinterpret_cast<const float4*>(src + off);
    float4 b = *reinterpret_cast<const float4*>(src + off + 4);
    short8v v = {f2bf(a.x), f2bf(a.y), f2bf(a.z), f2bf(a.w),
                 f2bf(b.x), f2bf(b.y), f2bf(b.z), f2bf(b.w)};
    *reinterpret_cast<short8v*>(dst + off) = v;
}

// ---------------- bf16 MFMA GEMM cores --------------------------------------
__device__ __forceinline__ void mgemm_core(const short* __restrict__ A,
                                           const short* __restrict__ Wb,
                                           f32x4 (&acc)[4][2],
                                           int mrow, int ncol, int Nact, int K) {
    const int lane = threadIdx.x & 63;
    const int koff = (lane >> 4) * 8;
    for (int k0 = 0; k0 < K; k0 += 32) {
        short8v af[4], bfr[2];
#pragma unroll
        for (int mf = 0; mf < 4; mf++)
            af[mf] = *reinterpret_cast<const short8v*>(
                A + (size_t)(mrow + mf * 16) * K + k0 + koff);
#pragma unroll
        for (int nf = 0; nf < 2; nf++) {
            int r = ncol + nf * 16;
            short8v z = {0, 0, 0, 0, 0, 0, 0, 0};
            bfr[nf] = (r < Nact)
                ? *reinterpret_cast<const short8v*>(Wb + (size_t)r * K + k0 + koff)
                : z;
        }
#pragma unroll
        for (int mf = 0; mf < 4; mf++)
#pragma unroll
            for (int nf = 0; nf < 2; nf++)
                acc[mf][nf] = __builtin_amdgcn_mfma_f32_16x16x32_bf16(
                    af[mf], bfr[nf], acc[mf][nf], 0, 0, 0);
    }
}

// f32-output GEMM (x_proj, out_proj)
__global__ __launch_bounds__(256) void k_mgemm_f(const short* __restrict__ A,
                                                 const short* __restrict__ Wb,
                                                 float* __restrict__ out0,
                                                 int Nact, int K) {
    const int m0 = blockIdx.x * 128, n0 = blockIdx.y * 64;
    const int wid = threadIdx.x >> 6, lane = threadIdx.x & 63;
    const int wm = wid >> 1, wn = wid & 1;
    f32x4 acc[4][2] = {};
    mgemm_core(A, Wb, acc, m0 + wm * 64 + (lane & 15), n0 + wn * 32 + (lane & 15),
               Nact, K);
    const int prow = (lane >> 4) * 4, pcol = lane & 15;
#pragma unroll
    for (int mf = 0; mf < 4; mf++) {
        int mbase = m0 + wm * 64 + mf * 16 + prow;
#pragma unroll
        for (int nf = 0; nf < 2; nf++) {
            int n = n0 + wn * 32 + nf * 16 + pcol;
            if (n >= Nact) continue;
#pragma unroll
            for (int r = 0; r < 4; r++)
                out0[(size_t)(mbase + r) * Nact + n] = acc[mf][nf][r];
        }
    }
}

// in_proj: split bf16 outputs (xf | z), each ldc=192
__global__ __launch_bounds__(256) void k_mgemm_in(const short* __restrict__ A,
                                                  const short* __restrict__ Wb,
                                                  short* __restrict__ xf_bf,
                                                  short* __restrict__ z_bf,
                                                  int K) {
    const int m0 = blockIdx.x * 128, n0 = blockIdx.y * 64;
    const int wid = threadIdx.x >> 6, lane = threadIdx.x & 63;
    const int wm = wid >> 1, wn = wid & 1;
    f32x4 acc[4][2] = {};
    mgemm_core(A, Wb, acc, m0 + wm * 64 + (lane & 15), n0 + wn * 32 + (lane & 15),
               384, K);
    const int prow = (lane >> 4) * 4, pcol = lane & 15;
#pragma unroll
    for (int mf = 0; mf < 4; mf++) {
        int mbase = m0 + wm * 64 + mf * 16 + prow;
#pragma unroll
        for (int nf = 0; nf < 2; nf++) {
            int n = n0 + wn * 32 + nf * 16 + pcol;
#pragma unroll
            for (int r = 0; r < 4; r++) {
                int m = mbase + r;
                if (n < 192) xf_bf[(size_t)m * 192 + n] = f2bf(acc[mf][nf][r]);
                else         z_bf[(size_t)m * 192 + (n - 192)] = f2bf(acc[mf][nf][r]);
            }
        }
    }
}

// ---------------- depthwise 3x3 conv + bias + SiLU ---------------------------
// 8-row strip x 4 channels per thread; 3x10 window loaded upfront (batched
// clause, one latency), border zeros via selects. Loads/output: 0.94.
__global__ __launch_bounds__(192) void k_conv(const short* __restrict__ xfb,
                                              const float* __restrict__ cw,
                                              const float* __restrict__ cb,
                                              short* __restrict__ xcb) {
    const int tid = threadIdx.x;
    const int dg = tid % 48;           // channel quad index
    const int wl = tid / 48;           // 0..3
    const int blk = blockIdx.x;        // ((b*8 + hq)*16 + wq)
    const int wq = blk & 15;
    const int hq = (blk >> 4) & 7;
    const int b  = blk >> 7;
    const int w  = wq * 4 + wl;
    const int d  = dg * 4;
    const int h0 = hq * 8;

    short4 win[3][10];
    const short4 z4 = make_short4(0, 0, 0, 0);
#pragma unroll
    for (int kw = 0; kw < 3; kw++) {
        int ww = w + kw - 1;
        bool wok = (unsigned)ww < (unsigned)W_;
        int wc = min(max(ww, 0), W_ - 1);
#pragma unroll
        for (int r = 0; r < 10; r++) {
            int hh = h0 - 1 + r;
            bool ok = wok && ((unsigned)hh < (unsigned)H_);
            int hc = min(max(hh, 0), H_ - 1);
            short4 v = *reinterpret_cast<const short4*>(
                xfb + (((size_t)b * H_ + hc) * W_ + wc) * Dn + d);
            win[kw][r] = ok ? v : z4;
        }
    }

    float wgt[4][9];
    float bias[4];
#pragma unroll
    for (int c = 0; c < 4; c++) {
        bias[c] = cb[d + c];
#pragma unroll
        for (int t = 0; t < 9; t++) wgt[c][t] = cw[(d + c) * 9 + t];
    }

#pragma unroll
    for (int j = 0; j < 8; j++) {
        float a0 = bias[0], a1 = bias[1], a2 = bias[2], a3 = bias[3];
#pragma unroll
        for (int kh = 0; kh < 3; kh++)
#pragma unroll
            for (int kw = 0; kw < 3; kw++) {
                short4 v = win[kw][j + kh];
                int t = kh * 3 + kw;
                a0 = fmaf(bf2f(v.x), wgt[0][t], a0);
                a1 = fmaf(bf2f(v.y), wgt[1][t], a1);
                a2 = fmaf(bf2f(v.z), wgt[2][t], a2);
                a3 = fmaf(bf2f(v.w), wgt[3][t], a3);
            }
        short4 o;
        o.x = f2bf(a0 / (1.f + __expf(-a0)));
        o.y = f2bf(a1 / (1.f + __expf(-a1)));
        o.z = f2bf(a2 / (1.f + __expf(-a2)));
        o.w = f2bf(a3 / (1.f + __expf(-a3)));
        *reinterpret_cast<short4*>(
            xcb + (((size_t)b * H_ + h0 + j) * W_ + w) * Dn + d) = o;
    }
}

// ---------------- per-step delta / e1 helper (branchless) -------------------
__device__ __forceinline__ void delta_e1(float x, float& delta, float& e1) {
    float t = __expf(fminf(x, 80.f));
    float opt = 1.f + t;
    delta = __logf(opt);
    e1 = __builtin_amdgcn_rcpf(opt);
}

// packed 12-term dot, 2 parallel chains of 3 pkfma
__device__ __forceinline__ float dot12p(const float4& q0, const float4& q1,
                                        const float4& q2, const f32x2* w2,
                                        float bias) {
    f32x2 a0 = pkfma(lo2(q0), w2[0], mk2(bias, 0.f));
    f32x2 a1 = lo2(q1) * w2[2];
    a0 = pkfma(hi2(q0), w2[1], a0);
    a1 = pkfma(hi2(q1), w2[3], a1);
    a0 = pkfma(lo2(q2), w2[4], a0);
    a1 = pkfma(hi2(q2), w2[5], a1);
    f32x2 s = a0 + a1;
    return s.x + s.y;
}

// scalar 12-term dot (general path)
__device__ __forceinline__ float dot12(const float4& a, const float4& b,
                                       const float4& c, const float* w, float x) {
    x = fmaf(a.x, w[0], x);  x = fmaf(a.y, w[1], x);
    x = fmaf(a.z, w[2], x);  x = fmaf(a.w, w[3], x);
    x = fmaf(b.x, w[4], x);  x = fmaf(b.y, w[5], x);
    x = fmaf(b.z, w[6], x);  x = fmaf(b.w, w[7], x);
    x = fmaf(c.x, w[8], x);  x = fmaf(c.y, w[9], x);
    x = fmaf(c.z, w[10], x); x = fmaf(c.w, w[11], x);
    return x;
}

// ---------------- scan phase 1: per-chunk (prod(a), h_partial) --------------
// Fast path software-pipelined in groups of GS=8: loop A (independent
// dot/softplus chains), loop B (serial h recurrence). Static indexing.
__global__ __launch_bounds__(192, 8) void k_scan1(const short* __restrict__ xcb,
                                               const float* __restrict__ xdbl,
                                               const float* __restrict__ dtw_all,
                                               const float* __restrict__ dtb_all,
                                               const float* __restrict__ alog,
                                               float* __restrict__ Aprod,
                                               float* __restrict__ hpart) {
    const int blk = blockIdx.x;            // ((b*K + k)*NC + c)
    const int c = blk % NC;
    const int k = (blk / NC) % K_;
    const int b = blk / (NC * K_);
    const int d = threadIdx.x;
    const int t0 = c * CS;
    const int stride = ((k & 1) ? 64 : 1) * ((k >= 2) ? -1 : 1);
    const int lm0 = map_t(k, t0);

    __shared__ float4 sx4[CS][5];
    const float4* xd4 = reinterpret_cast<const float4*>(xdbl);
    for (int i = d; i < CS * 5; i += 192) {
        int ts = i / 5, q = i % 5;
        sx4[ts][q] = xd4[((size_t)b * L_ + lm0 + ts * stride) * 28 + k * 7 + q];
    }
    __syncthreads();

    float dtw[R_];
#pragma unroll
    for (int r = 0; r < R_; r++) dtw[r] = dtw_all[((size_t)k * Dn + d) * R_ + r];
    f32x2 w2[6];
#pragma unroll
    for (int r = 0; r < 6; r++) w2[r] = mk2(dtw[2 * r], dtw[2 * r + 1]);
    const float bias = dtb_all[k * Dn + d];
    float Av[Nst];
    bool fast = true;
#pragma unroll
    for (int n = 0; n < Nst; n++) {
        Av[n] = -__expf(alog[((size_t)k * Dn + d) * Nst + n]);
        fast = fast && (fabsf(Av[n] + (float)(n + 1)) < 1e-3f);
    }

    const long stepD = (long)stride * Dn;
    const short* up = xcb + ((size_t)b * L_ + lm0) * Dn + d;
    size_t base = ((((size_t)(b * K_ + k) * NC + c) * Dn + d)) * Nst;

    if (fast) {
        f32x2 h01 = mk2(0.f, 0.f), h23 = h01, h45 = h01, h67 = h01;
        float p0 = 1.f, p1 = 1.f, p2_ = 1.f, p3_ = 1.f;
        for (int g = 0; g < CS / GS; ++g) {
            const short* ug = up + (long)g * GS * stepD;
            float e1a[GS], dua[GS];
            // loop A: independent chains (dot -> exp -> log -> rcp)
#pragma unroll
            for (int j = 0; j < GS; ++j) {
                int ts = g * GS + j;
                float u = bf2f(ug[(long)j * stepD]);
                float4 q0 = sx4[ts][0], q1 = sx4[ts][1], q2 = sx4[ts][2];
                float delta, e1; delta_e1(dot12p(q0, q1, q2, w2, bias), delta, e1);
                e1a[j] = e1;
                dua[j] = delta * u;
            }
            // loop B: serial h recurrence (only true loop-carried dep)
#pragma unroll
            for (int j = 0; j < GS; ++j) {
                int ts = g * GS + j;
                float e1 = e1a[j], du = dua[j];
                float4 qb0 = sx4[ts][3], qb1 = sx4[ts][4];
                float a2 = e1 * e1;
                f32x2 p12 = mk2(e1, a2);
                f32x2 a22 = mk2(a2, a2);
                f32x2 p34 = a22 * p12;
                f32x2 a44 = mk2(p34.y, p34.y);
                f32x2 p56 = a44 * p12;
                f32x2 p78 = a44 * p34;
                f32x2 du2 = mk2(du, du);
                h01 = pkfma(p12, h01, du2 * lo2(qb0));
                h23 = pkfma(p34, h23, du2 * hi2(qb0));
                h45 = pkfma(p56, h45, du2 * lo2(qb1));
                h67 = pkfma(p78, h67, du2 * hi2(qb1));
            }
            p0 *= e1a[0]; p1 *= e1a[1]; p2_ *= e1a[2]; p3_ *= e1a[3];
            p0 *= e1a[4]; p1 *= e1a[5]; p2_ *= e1a[6]; p3_ *= e1a[7];
        }
        float e1p = (p0 * p1) * (p2_ * p3_);
        float p2 = e1p * e1p, p3 = p2 * e1p, p4 = p2 * p2;
        float4* ap4 = reinterpret_cast<float4*>(Aprod + base);
        ap4[0] = make_float4(e1p, p2, p3, p4);
        ap4[1] = make_float4(p4 * e1p, p4 * p2, p4 * p3, p4 * p4);
        float4* hp4 = reinterpret_cast<float4*>(hpart + base);
        hp4[0] = make_float4(h01.x, h01.y, h23.x, h23.y);
        hp4[1] = make_float4(h45.x, h45.y, h67.x, h67.y);
    } else {
        float h[Nst] = {};
        float Ap[Nst];
#pragma unroll
        for (int n = 0; n < Nst; n++) Ap[n] = 1.f;
        float u_next = bf2f(*up);
        const short* upp = up;
        for (int ts = 0; ts < CS; ts++) {
            float u = u_next;
            upp += stepD;
            if (ts + 1 < CS) u_next = bf2f(*upp);
            float4 q0 = sx4[ts][0], q1 = sx4[ts][1], q2 = sx4[ts][2];
            float4 qb0 = sx4[ts][3], qb1 = sx4[ts][4];
            float Bv[Nst] = {qb0.x, qb0.y, qb0.z, qb0.w, qb1.x, qb1.y, qb1.z, qb1.w};
            float delta, e1; delta_e1(dot12(q0, q1, q2, dtw, bias), delta, e1);
            float du = delta * u;
#pragma unroll
            for (int n = 0; n < Nst; n++) {
                float a = __expf(delta * Av[n]);
                Ap[n] *= a;
                h[n] = fmaf(a, h[n], du * Bv[n]);
            }
        }
#pragma unroll
        for (int n = 0; n < Nst; n++) { Aprod[base + n] = Ap[n]; hpart[base + n] = h[n]; }
    }
}

// ---------------- scan phase 2: chunk-level recurrence -----------------------
__global__ __launch_bounds__(256) void k_scan2(const float* __restrict__ Aprod,
                                               const float* __restrict__ hpart,
                                               float* __restrict__ hin) {
    int idx = blockIdx.x * 256 + threadIdx.x;   // B*K*Dn*Nst = 49152
    int dn = idx % (Dn * Nst);
    int bk = idx / (Dn * Nst);
    size_t stride = (size_t)Dn * Nst;
    size_t base = (size_t)bk * NC * stride + dn;
    float h = 0.f;
    for (int cc = 0; cc < NC; cc++) {
        size_t s = base + (size_t)cc * stride;
        hin[s] = h;
        h = fmaf(Aprod[s], h, hpart[s]);
    }
}

// ---------------- scan phase 3: recompute with h_in, emit y -----------------
__global__ __launch_bounds__(192, 8) void k_scan3(const short* __restrict__ xcb,
                                               const float* __restrict__ xdbl,
                                               const float* __restrict__ dtw_all,
                                               const float* __restrict__ dtb_all,
                                               const float* __restrict__ alog,
                                               const float* __restrict__ dvec,
                                               const float* __restrict__ hin,
                                               short* __restrict__ y0,
                                               short* __restrict__ y1,
                                               short* __restrict__ y2,
                                               short* __restrict__ y3) {
    const int blk = blockIdx.x;
    const int c = blk % NC;
    const int k = (blk / NC) % K_;
    const int b = blk / (NC * K_);
    const int d = threadIdx.x;
    const int t0 = c * CS;
    const int stride = ((k & 1) ? 64 : 1) * ((k >= 2) ? -1 : 1);
    const int lm0 = map_t(k, t0);
    short* __restrict__ yk = (k == 0) ? y0 : (k == 1) ? y1 : (k == 2) ? y2 : y3;

    __shared__ float4 sx4[CS][7];
    const float4* xd4 = reinterpret_cast<const float4*>(xdbl);
    for (int i = d; i < CS * 7; i += 192) {
        int ts = i / 7, q = i % 7;
        sx4[ts][q] = xd4[((size_t)b * L_ + lm0 + ts * stride) * 28 + k * 7 + q];
    }
    __syncthreads();

    float dtw[R_];
#pragma unroll
    for (int r = 0; r < R_; r++) dtw[r] = dtw_all[((size_t)k * Dn + d) * R_ + r];
    f32x2 w2[6];
#pragma unroll
    for (int r = 0; r < 6; r++) w2[r] = mk2(dtw[2 * r], dtw[2 * r + 1]);
    const float bias = dtb_all[k * Dn + d];
    const float Dk = dvec[k * Dn + d];
    float Av[Nst];
    bool fast = true;
#pragma unroll
    for (int n = 0; n < Nst; n++) {
        Av[n] = -__expf(alog[((size_t)k * Dn + d) * Nst + n]);
        fast = fast && (fabsf(Av[n] + (float)(n + 1)) < 1e-3f);
    }

    size_t hbase = ((((size_t)(b * K_ + k) * NC + c) * Dn + d)) * Nst;
    const long stepD = (long)stride * Dn;
    const short* up = xcb + ((size_t)b * L_ + lm0) * Dn + d;
    short* yp = yk + ((size_t)b * L_ + lm0) * Dn + d;

    if (fast) {
        const float4* hi4 = reinterpret_cast<const float4*>(hin + hbase);
        float4 ha = hi4[0], hb = hi4[1];
        f32x2 h01 = lo2(ha), h23 = hi2(ha), h45 = lo2(hb), h67 = hi2(hb);
        for (int g = 0; g < CS / GS; ++g) {
            const short* ug = up + (long)g * GS * stepD;
            short* yg = yp + (long)g * GS * stepD;
            float e1a[GS], dua[GS], dku[GS];
            // loop A: independent chains
#pragma unroll
            for (int j = 0; j < GS; ++j) {
                int ts = g * GS + j;
                float u = bf2f(ug[(long)j * stepD]);
                float4 q0 = sx4[ts][0], q1 = sx4[ts][1], q2 = sx4[ts][2];
                float delta, e1; delta_e1(dot12p(q0, q1, q2, w2, bias), delta, e1);
                e1a[j] = e1;
                dua[j] = delta * u;
                dku[j] = Dk * u;
            }
            // loop B: serial h recurrence + y emission
#pragma unroll
            for (int j = 0; j < GS; ++j) {
                int ts = g * GS + j;
                float e1 = e1a[j], du = dua[j];
                float4 qb0 = sx4[ts][3], qb1 = sx4[ts][4];
                float4 qc0 = sx4[ts][5], qc1 = sx4[ts][6];
                float a2 = e1 * e1;
                f32x2 p12 = mk2(e1, a2);
                f32x2 a22 = mk2(a2, a2);
                f32x2 p34 = a22 * p12;
                f32x2 a44 = mk2(p34.y, p34.y);
                f32x2 p56 = a44 * p12;
                f32x2 p78 = a44 * p34;
                f32x2 du2 = mk2(du, du);
                h01 = pkfma(p12, h01, du2 * lo2(qb0));
                h23 = pkfma(p34, h23, du2 * hi2(qb0));
                h45 = pkfma(p56, h45, du2 * lo2(qb1));
                h67 = pkfma(p78, h67, du2 * hi2(qb1));
                f32x2 yacc = mk2(dku[j], 0.f);
                yacc = pkfma(h01, lo2(qc0), yacc);
                yacc = pkfma(h23, hi2(qc0), yacc);
                yacc = pkfma(h45, lo2(qc1), yacc);
                yacc = pkfma(h67, hi2(qc1), yacc);
                yg[(long)j * stepD] = f2bf(yacc.x + yacc.y);
            }
        }
    } else {
        float h[Nst];
#pragma unroll
        for (int n = 0; n < Nst; n++) h[n] = hin[hbase + n];
        float u_next = bf2f(*up);
        const short* upp = up;
        short* ypp = yp;
        for (int ts = 0; ts < CS; ts++) {
            float u = u_next;
            upp += stepD;
            if (ts + 1 < CS) u_next = bf2f(*upp);
            float4 q0 = sx4[ts][0], q1 = sx4[ts][1], q2 = sx4[ts][2];
            float4 qb0 = sx4[ts][3], qb1 = sx4[ts][4];
            float4 qc0 = sx4[ts][5], qc1 = sx4[ts][6];
            float Bv[Nst] = {qb0.x, qb0.y, qb0.z, qb0.w, qb1.x, qb1.y, qb1.z, qb1.w};
            float Cv[Nst] = {qc0.x, qc0.y, qc0.z, qc0.w, qc1.x, qc1.y, qc1.z, qc1.w};
            float delta, e1; delta_e1(dot12(q0, q1, q2, dtw, bias), delta, e1);
            float du = delta * u;
            float y = Dk * u;
#pragma unroll
            for (int n = 0; n < Nst; n++) {
                float a = __expf(delta * Av[n]);
                h[n] = fmaf(a, h[n], du * Bv[n]);
                y = fmaf(h[n], Cv[n], y);
            }
            *ypp = f2bf(y);
            ypp += stepD;
        }
    }
}

// ---------------- merge 4 dirs + LayerNorm(Dn) * SiLU(z) -> bf16 ------------
__global__ __launch_bounds__(256) void k_ln(const short* __restrict__ y0,
                                            const short* __restrict__ y1,
                                            const short* __restrict__ y2,
                                            const short* __restrict__ y3,
                                            const short* __restrict__ zb,
                                            const float* __restrict__ lnw,
                                            const float* __restrict__ lnb,
                                            short* __restrict__ yfin) {
    const int row = blockIdx.x * 4 + (threadIdx.x >> 6);
    const int lane = threadIdx.x & 63;
    const size_t base = (size_t)row * Dn;
    float v[3];
    float s = 0.f, s2 = 0.f;
#pragma unroll
    for (int j = 0; j < 3; j++) {
        size_t idx = base + lane + j * 64;
        v[j] = bf2f(y0[idx]) + bf2f(y1[idx]) + bf2f(y2[idx]) + bf2f(y3[idx]);
        s += v[j];
        s2 = fmaf(v[j], v[j], s2);
    }
#pragma unroll
    for (int o = 1; o < 64; o <<= 1) {
        s += __shfl_xor(s, o);
        s2 += __shfl_xor(s2, o);
    }
    const float inv = 1.f / 192.f;
    float mu = s * inv;
    float var = s2 * inv - mu * mu;
    float rstd = rsqrtf(var + 1e-5f);
#pragma unroll
    for (int j = 0; j < 3; j++) {
        int dd = lane + j * 64;
        size_t idx = base + dd;
        float zz = bf2f(zb[idx]);
        float sig = 1.f / (1.f + __expf(-zz));
        float res = ((v[j] - mu) * rstd * lnw[dd] + lnb[dd]) * (zz * sig);
        yfin[idx] = f2bf(res);
    }
}

// ---------------- launcher ---------------------------------------------------
extern "C" void kernel_launch(void* const* d_in, const int* in_sizes, int n_in,
                              void* d_out, int out_size, void* d_ws, size_t ws_size,
                              hipStream_t stream) {
    const float* x    = (const float*)d_in[0];
    const float* w_in = (const float*)d_in[1];
    const float* cw   = (const float*)d_in[2];
    const float* cb   = (const float*)d_in[3];
    const float* xpw  = (const float*)d_in[4];
    const float* dtw  = (const float*)d_in[5];
    const float* dtb  = (const float*)d_in[6];
    const float* alog = (const float*)d_in[7];
    const float* dvec = (const float*)d_in[8];
    const float* lnw  = (const float*)d_in[9];
    const float* lnb  = (const float*)d_in[10];
    const float* wout = (const float*)d_in[11];
    float* out = (float*)d_out;

    const size_t SH  = (size_t)MROWS * Dn;               // 6,291,456 elems
    const size_t SCN = (size_t)B_ * K_ * NC * Dn * Nst;  // 6,291,456 elems

    char* p = (char*)d_ws;
    short* x_bf  = (short*)p; p += SH * 2;               // region0 -> y0
    short* xf_bf = (short*)p; p += SH * 2;               // region1 -> y1
    short* z_bf  = (short*)p; p += SH * 2;               // region2
    short* xc_bf = (short*)p; p += SH * 2;               // region3
    float* xdbl  = (float*)p; p += (size_t)MROWS * (K_ * CPROJ) * 4;
    float* Aprod = (float*)p; p += SCN * 4;              // region5 -> y2
    float* hpart = (float*)p; p += SCN * 4;              // region6 -> y3
    float* hin   = (float*)p; p += SCN * 4;              // region7 -> yfin
    short* w_bf  = (short*)p;
    // aliases (lifetimes): y0<-x_bf (dead after in_proj), y1<-xf_bf (dead after
    // conv), y2<-Aprod, y3<-hpart (dead after scan2), yfin<-hin (dead after
    // scan3; k_ln runs after scan3).
    short* y0 = x_bf;
    short* y1 = xf_bf;
    short* y2 = (short*)Aprod;
    short* y3 = (short*)hpart;
    short* yfin_bf = (short*)hin;

    // 0. fused converts
    k_cvt<<<(XUNITS + WUNITS + 255) / 256, 256, 0, stream>>>(x, w_in, xpw, wout,
                                                             x_bf, w_bf);
    // 1. in_proj (MFMA) -> xf_bf, z_bf
    k_mgemm_in<<<dim3(MROWS / 128, 6), 256, 0, stream>>>(x_bf, w_bf + WOFF_IN,
                                                         xf_bf, z_bf, C_);
    // 2. depthwise conv 3x3 + SiLU -> xc_bf (8-row strip x 4 ch per thread)
    k_conv<<<B_ * (H_ / 8) * (W_ / 4), 192, 0, stream>>>(xf_bf, cw, cb, xc_bf);
    // 3. x_dbl (all 4 dirs, one MFMA GEMM) -> f32
    k_mgemm_f<<<dim3(MROWS / 128, 2), 256, 0, stream>>>(xc_bf, w_bf + WOFF_XP,
                                                        xdbl, K_ * CPROJ, Dn);
    // 4-6. chunked parallel selective scan (CS=32, software-pipelined groups)
    k_scan1<<<B_ * K_ * NC, 192, 0, stream>>>(xc_bf, xdbl, dtw, dtb, alog, Aprod, hpart);
    k_scan2<<<(B_ * K_ * Dn * Nst) / 256, 256, 0, stream>>>(Aprod, hpart, hin);
    k_scan3<<<B_ * K_ * NC, 192, 0, stream>>>(xc_bf, xdbl, dtw, dtb, alog, dvec,
                                              hin, y0, y1, y2, y3);
    // 7. merge + LayerNorm * SiLU(z) -> bf16
    k_ln<<<MROWS / 4, 256, 0, stream>>>(y0, y1, y2, y3, z_bf, lnw, lnb, yfin_bf);
    // 8. out_proj (MFMA) -> d_out (f32)
    k_mgemm_f<<<dim3(MROWS / 128, 3), 256, 0, stream>>>(yfin_bf, w_bf + WOFF_OUT,
                                                        out, C_, Dn);
}

// Round 16
// 201.546 us; speedup vs baseline: 1.3006x; 1.3006x over previous
//
#include <hip/hip_runtime.h>
#include <hip/hip_bf16.h>

// ---------------- problem constants (fixed by setup_inputs) ----------------
constexpr int B_  = 8;
constexpr int H_  = 64;
constexpr int W_  = 64;
constexpr int C_  = 192;
constexpr int Dn  = 192;
constexpr int Nst = 8;    // state dim N
constexpr int R_  = 12;
constexpr int K_  = 4;    // directions
constexpr int L_  = H_ * W_;          // 4096
constexpr int CS  = 32;               // scan chunk size
constexpr int GS  = 8;                // pipeline group size (CS % GS == 0)
constexpr int NC  = L_ / CS;          // 128 chunks
constexpr int CPROJ = R_ + 2 * Nst;   // 28
constexpr int MROWS = B_ * L_;        // 32768

typedef __attribute__((ext_vector_type(8))) short short8v;
typedef __attribute__((ext_vector_type(4))) float f32x4;
typedef __attribute__((ext_vector_type(2))) float f32x2;

// t -> spatial position for direction k (verified round 0).
// Within a chunk: lm = map_t(k,t0) + ts*stride (no wrap since CS | 64).
__device__ __forceinline__ int map_t(int k, int t) {
    int tt = (k >= 2) ? (L_ - 1 - t) : t;
    if (k & 1) tt = (tt & 63) * 64 + (tt >> 6);
    return tt;
}

__device__ __forceinline__ short f2bf(float f) {   // round-to-nearest-even
    unsigned u = __float_as_uint(f);
    u += 0x7FFFu + ((u >> 16) & 1u);
    return (short)(u >> 16);
}
__device__ __forceinline__ float bf2f(short s) {
    return __uint_as_float(((unsigned)(unsigned short)s) << 16);
}

// packed fp32 helpers (v_pk_fma_f32 / v_pk_mul_f32 on gfx950)
__device__ __forceinline__ f32x2 mk2(float a, float b) { f32x2 v; v.x = a; v.y = b; return v; }
__device__ __forceinline__ f32x2 lo2(float4 v) { return mk2(v.x, v.y); }
__device__ __forceinline__ f32x2 hi2(float4 v) { return mk2(v.z, v.w); }
__device__ __forceinline__ f32x2 pkfma(f32x2 a, f32x2 b, f32x2 c) {
    return __builtin_elementwise_fma(a, b, c);
}

// ---------------- fused f32 -> bf16 convert (x and all weights) -------------
constexpr int WOFF_IN  = 0;               // w_in  (384x192)
constexpr int WOFF_XP  = 73728;           // xpw   (112x192)
constexpr int WOFF_OUT = 95232;           // wout  (192x192)
constexpr int WTOTAL   = 132096;
constexpr int XUNITS   = MROWS * Dn / 8;  // 786432
constexpr int WUNITS   = WTOTAL / 8;      // 16512
__global__ __launch_bounds__(256) void k_cvt(const float* __restrict__ x,
                                             const float* __restrict__ w_in,
                                             const float* __restrict__ xpw,
                                             const float* __restrict__ wout,
                                             short* __restrict__ x_bf,
                                             short* __restrict__ w_bf) {
    int g = blockIdx.x * 256 + threadIdx.x;
    const float* src;
    short* dst;
    int off;
    if (g < XUNITS) { src = x; dst = x_bf; off = g * 8; }
    else {
        g -= XUNITS;
        if (g >= WUNITS) return;
        int base = g * 8;
        dst = w_bf; off = base;
        if (base < WOFF_XP)       { src = w_in; }
        else if (base < WOFF_OUT) { src = xpw;  src -= WOFF_XP; }
        else                      { src = wout; src -= WOFF_OUT; }
    }
    float4 a = *reinterpret_cast<const float4*>(src + off);
    float4 b = *reinterpret_cast<const float4*>(src + off + 4);
    short8v v = {f2bf(a.x), f2bf(a.y), f2bf(a.z), f2bf(a.w),
                 f2bf(b.x), f2bf(b.y), f2bf(b.z), f2bf(b.w)};
    *reinterpret_cast<short8v*>(dst + off) = v;
}

// ---------------- bf16 MFMA GEMM cores --------------------------------------
__device__ __forceinline__ void mgemm_core(const short* __restrict__ A,
                                           const short* __restrict__ Wb,
                                           f32x4 (&acc)[4][2],
                                           int mrow, int ncol, int Nact, int K) {
    const int lane = threadIdx.x & 63;
    const int koff = (lane >> 4) * 8;
    for (int k0 = 0; k0 < K; k0 += 32) {
        short8v af[4], bfr[2];
#pragma unroll
        for (int mf = 0; mf < 4; mf++)
            af[mf] = *reinterpret_cast<const short8v*>(
                A + (size_t)(mrow + mf * 16) * K + k0 + koff);
#pragma unroll
        for (int nf = 0; nf < 2; nf++) {
            int r = ncol + nf * 16;
            short8v z = {0, 0, 0, 0, 0, 0, 0, 0};
            bfr[nf] = (r < Nact)
                ? *reinterpret_cast<const short8v*>(Wb + (size_t)r * K + k0 + koff)
                : z;
        }
#pragma unroll
        for (int mf = 0; mf < 4; mf++)
#pragma unroll
            for (int nf = 0; nf < 2; nf++)
                acc[mf][nf] = __builtin_amdgcn_mfma_f32_16x16x32_bf16(
                    af[mf], bfr[nf], acc[mf][nf], 0, 0, 0);
    }
}

// f32-output GEMM (x_proj, out_proj)
__global__ __launch_bounds__(256) void k_mgemm_f(const short* __restrict__ A,
                                                 const short* __restrict__ Wb,
                                                 float* __restrict__ out0,
                                                 int Nact, int K) {
    const int m0 = blockIdx.x * 128, n0 = blockIdx.y * 64;
    const int wid = threadIdx.x >> 6, lane = threadIdx.x & 63;
    const int wm = wid >> 1, wn = wid & 1;
    f32x4 acc[4][2] = {};
    mgemm_core(A, Wb, acc, m0 + wm * 64 + (lane & 15), n0 + wn * 32 + (lane & 15),
               Nact, K);
    const int prow = (lane >> 4) * 4, pcol = lane & 15;
#pragma unroll
    for (int mf = 0; mf < 4; mf++) {
        int mbase = m0 + wm * 64 + mf * 16 + prow;
#pragma unroll
        for (int nf = 0; nf < 2; nf++) {
            int n = n0 + wn * 32 + nf * 16 + pcol;
            if (n >= Nact) continue;
#pragma unroll
            for (int r = 0; r < 4; r++)
                out0[(size_t)(mbase + r) * Nact + n] = acc[mf][nf][r];
        }
    }
}

// in_proj: split bf16 outputs (xf | z), each ldc=192
__global__ __launch_bounds__(256) void k_mgemm_in(const short* __restrict__ A,
                                                  const short* __restrict__ Wb,
                                                  short* __restrict__ xf_bf,
                                                  short* __restrict__ z_bf,
                                                  int K) {
    const int m0 = blockIdx.x * 128, n0 = blockIdx.y * 64;
    const int wid = threadIdx.x >> 6, lane = threadIdx.x & 63;
    const int wm = wid >> 1, wn = wid & 1;
    f32x4 acc[4][2] = {};
    mgemm_core(A, Wb, acc, m0 + wm * 64 + (lane & 15), n0 + wn * 32 + (lane & 15),
               384, K);
    const int prow = (lane >> 4) * 4, pcol = lane & 15;
#pragma unroll
    for (int mf = 0; mf < 4; mf++) {
        int mbase = m0 + wm * 64 + mf * 16 + prow;
#pragma unroll
        for (int nf = 0; nf < 2; nf++) {
            int n = n0 + wn * 32 + nf * 16 + pcol;
#pragma unroll
            for (int r = 0; r < 4; r++) {
                int m = mbase + r;
                if (n < 192) xf_bf[(size_t)m * 192 + n] = f2bf(acc[mf][nf][r]);
                else         z_bf[(size_t)m * 192 + (n - 192)] = f2bf(acc[mf][nf][r]);
            }
        }
    }
}

// ---------------- depthwise 3x3 conv + bias + SiLU ---------------------------
// 8-row strip x 4 channels per thread; 3x10 window loaded upfront (batched
// clause, one latency), border zeros via selects. Loads/output: 0.94.
__global__ __launch_bounds__(192) void k_conv(const short* __restrict__ xfb,
                                              const float* __restrict__ cw,
                                              const float* __restrict__ cb,
                                              short* __restrict__ xcb) {
    const int tid = threadIdx.x;
    const int dg = tid % 48;           // channel quad index
    const int wl = tid / 48;           // 0..3
    const int blk = blockIdx.x;        // ((b*8 + hq)*16 + wq)
    const int wq = blk & 15;
    const int hq = (blk >> 4) & 7;
    const int b  = blk >> 7;
    const int w  = wq * 4 + wl;
    const int d  = dg * 4;
    const int h0 = hq * 8;

    short4 win[3][10];
    const short4 z4 = make_short4(0, 0, 0, 0);
#pragma unroll
    for (int kw = 0; kw < 3; kw++) {
        int ww = w + kw - 1;
        bool wok = (unsigned)ww < (unsigned)W_;
        int wc = min(max(ww, 0), W_ - 1);
#pragma unroll
        for (int r = 0; r < 10; r++) {
            int hh = h0 - 1 + r;
            bool ok = wok && ((unsigned)hh < (unsigned)H_);
            int hc = min(max(hh, 0), H_ - 1);
            short4 v = *reinterpret_cast<const short4*>(
                xfb + (((size_t)b * H_ + hc) * W_ + wc) * Dn + d);
            win[kw][r] = ok ? v : z4;
        }
    }

    float wgt[4][9];
    float bias[4];
#pragma unroll
    for (int c = 0; c < 4; c++) {
        bias[c] = cb[d + c];
#pragma unroll
        for (int t = 0; t < 9; t++) wgt[c][t] = cw[(d + c) * 9 + t];
    }

#pragma unroll
    for (int j = 0; j < 8; j++) {
        float a0 = bias[0], a1 = bias[1], a2 = bias[2], a3 = bias[3];
#pragma unroll
        for (int kh = 0; kh < 3; kh++)
#pragma unroll
            for (int kw = 0; kw < 3; kw++) {
                short4 v = win[kw][j + kh];
                int t = kh * 3 + kw;
                a0 = fmaf(bf2f(v.x), wgt[0][t], a0);
                a1 = fmaf(bf2f(v.y), wgt[1][t], a1);
                a2 = fmaf(bf2f(v.z), wgt[2][t], a2);
                a3 = fmaf(bf2f(v.w), wgt[3][t], a3);
            }
        short4 o;
        o.x = f2bf(a0 / (1.f + __expf(-a0)));
        o.y = f2bf(a1 / (1.f + __expf(-a1)));
        o.z = f2bf(a2 / (1.f + __expf(-a2)));
        o.w = f2bf(a3 / (1.f + __expf(-a3)));
        *reinterpret_cast<short4*>(
            xcb + (((size_t)b * H_ + h0 + j) * W_ + w) * Dn + d) = o;
    }
}

// ---------------- per-step delta / e1 helper (branchless) -------------------
__device__ __forceinline__ void delta_e1(float x, float& delta, float& e1) {
    float t = __expf(fminf(x, 80.f));
    float opt = 1.f + t;
    delta = __logf(opt);
    e1 = __builtin_amdgcn_rcpf(opt);
}

// packed 12-term dot, 2 parallel chains of 3 pkfma
__device__ __forceinline__ float dot12p(const float4& q0, const float4& q1,
                                        const float4& q2, const f32x2* w2,
                                        float bias) {
    f32x2 a0 = pkfma(lo2(q0), w2[0], mk2(bias, 0.f));
    f32x2 a1 = lo2(q1) * w2[2];
    a0 = pkfma(hi2(q0), w2[1], a0);
    a1 = pkfma(hi2(q1), w2[3], a1);
    a0 = pkfma(lo2(q2), w2[4], a0);
    a1 = pkfma(hi2(q2), w2[5], a1);
    f32x2 s = a0 + a1;
    return s.x + s.y;
}

// scalar 12-term dot (general path)
__device__ __forceinline__ float dot12(const float4& a, const float4& b,
                                       const float4& c, const float* w, float x) {
    x = fmaf(a.x, w[0], x);  x = fmaf(a.y, w[1], x);
    x = fmaf(a.z, w[2], x);  x = fmaf(a.w, w[3], x);
    x = fmaf(b.x, w[4], x);  x = fmaf(b.y, w[5], x);
    x = fmaf(b.z, w[6], x);  x = fmaf(b.w, w[7], x);
    x = fmaf(c.x, w[8], x);  x = fmaf(c.y, w[9], x);
    x = fmaf(c.z, w[10], x); x = fmaf(c.w, w[11], x);
    return x;
}

// ---------------- scan phase 1: per-chunk (prod(a), h_partial) --------------
// Fast path software-pipelined in groups of GS=8: loop A (independent
// dot/softplus chains), loop B (serial h recurrence). Static indexing.
// NOTE: __launch_bounds__(192, 4) is load-bearing — (192,8) forces VGPR=32 and
// scratch-spills (r15: WRITE 171MB); no hint / dual-chunk variants also lose.
__global__ __launch_bounds__(192, 4) void k_scan1(const short* __restrict__ xcb,
                                               const float* __restrict__ xdbl,
                                               const float* __restrict__ dtw_all,
                                               const float* __restrict__ dtb_all,
                                               const float* __restrict__ alog,
                                               float* __restrict__ Aprod,
                                               float* __restrict__ hpart) {
    const int blk = blockIdx.x;            // ((b*K + k)*NC + c)
    const int c = blk % NC;
    const int k = (blk / NC) % K_;
    const int b = blk / (NC * K_);
    const int d = threadIdx.x;
    const int t0 = c * CS;
    const int stride = ((k & 1) ? 64 : 1) * ((k >= 2) ? -1 : 1);
    const int lm0 = map_t(k, t0);

    __shared__ float4 sx4[CS][5];
    const float4* xd4 = reinterpret_cast<const float4*>(xdbl);
    for (int i = d; i < CS * 5; i += 192) {
        int ts = i / 5, q = i % 5;
        sx4[ts][q] = xd4[((size_t)b * L_ + lm0 + ts * stride) * 28 + k * 7 + q];
    }
    __syncthreads();

    float dtw[R_];
#pragma unroll
    for (int r = 0; r < R_; r++) dtw[r] = dtw_all[((size_t)k * Dn + d) * R_ + r];
    f32x2 w2[6];
#pragma unroll
    for (int r = 0; r < 6; r++) w2[r] = mk2(dtw[2 * r], dtw[2 * r + 1]);
    const float bias = dtb_all[k * Dn + d];
    float Av[Nst];
    bool fast = true;
#pragma unroll
    for (int n = 0; n < Nst; n++) {
        Av[n] = -__expf(alog[((size_t)k * Dn + d) * Nst + n]);
        fast = fast && (fabsf(Av[n] + (float)(n + 1)) < 1e-3f);
    }

    const long stepD = (long)stride * Dn;
    const short* up = xcb + ((size_t)b * L_ + lm0) * Dn + d;
    size_t base = ((((size_t)(b * K_ + k) * NC + c) * Dn + d)) * Nst;

    if (fast) {
        f32x2 h01 = mk2(0.f, 0.f), h23 = h01, h45 = h01, h67 = h01;
        float p0 = 1.f, p1 = 1.f, p2_ = 1.f, p3_ = 1.f;
        for (int g = 0; g < CS / GS; ++g) {
            const short* ug = up + (long)g * GS * stepD;
            float e1a[GS], dua[GS];
            // loop A: independent chains (dot -> exp -> log -> rcp)
#pragma unroll
            for (int j = 0; j < GS; ++j) {
                int ts = g * GS + j;
                float u = bf2f(ug[(long)j * stepD]);
                float4 q0 = sx4[ts][0], q1 = sx4[ts][1], q2 = sx4[ts][2];
                float delta, e1; delta_e1(dot12p(q0, q1, q2, w2, bias), delta, e1);
                e1a[j] = e1;
                dua[j] = delta * u;
            }
            // loop B: serial h recurrence (only true loop-carried dep)
#pragma unroll
            for (int j = 0; j < GS; ++j) {
                int ts = g * GS + j;
                float e1 = e1a[j], du = dua[j];
                float4 qb0 = sx4[ts][3], qb1 = sx4[ts][4];
                float a2 = e1 * e1;
                f32x2 p12 = mk2(e1, a2);
                f32x2 a22 = mk2(a2, a2);
                f32x2 p34 = a22 * p12;
                f32x2 a44 = mk2(p34.y, p34.y);
                f32x2 p56 = a44 * p12;
                f32x2 p78 = a44 * p34;
                f32x2 du2 = mk2(du, du);
                h01 = pkfma(p12, h01, du2 * lo2(qb0));
                h23 = pkfma(p34, h23, du2 * hi2(qb0));
                h45 = pkfma(p56, h45, du2 * lo2(qb1));
                h67 = pkfma(p78, h67, du2 * hi2(qb1));
            }
            p0 *= e1a[0]; p1 *= e1a[1]; p2_ *= e1a[2]; p3_ *= e1a[3];
            p0 *= e1a[4]; p1 *= e1a[5]; p2_ *= e1a[6]; p3_ *= e1a[7];
        }
        float e1p = (p0 * p1) * (p2_ * p3_);
        float p2 = e1p * e1p, p3 = p2 * e1p, p4 = p2 * p2;
        float4* ap4 = reinterpret_cast<float4*>(Aprod + base);
        ap4[0] = make_float4(e1p, p2, p3, p4);
        ap4[1] = make_float4(p4 * e1p, p4 * p2, p4 * p3, p4 * p4);
        float4* hp4 = reinterpret_cast<float4*>(hpart + base);
        hp4[0] = make_float4(h01.x, h01.y, h23.x, h23.y);
        hp4[1] = make_float4(h45.x, h45.y, h67.x, h67.y);
    } else {
        float h[Nst] = {};
        float Ap[Nst];
#pragma unroll
        for (int n = 0; n < Nst; n++) Ap[n] = 1.f;
        float u_next = bf2f(*up);
        const short* upp = up;
        for (int ts = 0; ts < CS; ts++) {
            float u = u_next;
            upp += stepD;
            if (ts + 1 < CS) u_next = bf2f(*upp);
            float4 q0 = sx4[ts][0], q1 = sx4[ts][1], q2 = sx4[ts][2];
            float4 qb0 = sx4[ts][3], qb1 = sx4[ts][4];
            float Bv[Nst] = {qb0.x, qb0.y, qb0.z, qb0.w, qb1.x, qb1.y, qb1.z, qb1.w};
            float delta, e1; delta_e1(dot12(q0, q1, q2, dtw, bias), delta, e1);
            float du = delta * u;
#pragma unroll
            for (int n = 0; n < Nst; n++) {
                float a = __expf(delta * Av[n]);
                Ap[n] *= a;
                h[n] = fmaf(a, h[n], du * Bv[n]);
            }
        }
#pragma unroll
        for (int n = 0; n < Nst; n++) { Aprod[base + n] = Ap[n]; hpart[base + n] = h[n]; }
    }
}

// ---------------- scan phase 2: chunk-level recurrence -----------------------
__global__ __launch_bounds__(256) void k_scan2(const float* __restrict__ Aprod,
                                               const float* __restrict__ hpart,
                                               float* __restrict__ hin) {
    int idx = blockIdx.x * 256 + threadIdx.x;   // B*K*Dn*Nst = 49152
    int dn = idx % (Dn * Nst);
    int bk = idx / (Dn * Nst);
    size_t stride = (size_t)Dn * Nst;
    size_t base = (size_t)bk * NC * stride + dn;
    float h = 0.f;
    for (int cc = 0; cc < NC; cc++) {
        size_t s = base + (size_t)cc * stride;
        hin[s] = h;
        h = fmaf(Aprod[s], h, hpart[s]);
    }
}

// ---------------- scan phase 3: recompute with h_in, emit y -----------------
__global__ __launch_bounds__(192, 4) void k_scan3(const short* __restrict__ xcb,
                                               const float* __restrict__ xdbl,
                                               const float* __restrict__ dtw_all,
                                               const float* __restrict__ dtb_all,
                                               const float* __restrict__ alog,
                                               const float* __restrict__ dvec,
                                               const float* __restrict__ hin,
                                               short* __restrict__ y0,
                                               short* __restrict__ y1,
                                               short* __restrict__ y2,
                                               short* __restrict__ y3) {
    const int blk = blockIdx.x;
    const int c = blk % NC;
    const int k = (blk / NC) % K_;
    const int b = blk / (NC * K_);
    const int d = threadIdx.x;
    const int t0 = c * CS;
    const int stride = ((k & 1) ? 64 : 1) * ((k >= 2) ? -1 : 1);
    const int lm0 = map_t(k, t0);
    short* __restrict__ yk = (k == 0) ? y0 : (k == 1) ? y1 : (k == 2) ? y2 : y3;

    __shared__ float4 sx4[CS][7];
    const float4* xd4 = reinterpret_cast<const float4*>(xdbl);
    for (int i = d; i < CS * 7; i += 192) {
        int ts = i / 7, q = i % 7;
        sx4[ts][q] = xd4[((size_t)b * L_ + lm0 + ts * stride) * 28 + k * 7 + q];
    }
    __syncthreads();

    float dtw[R_];
#pragma unroll
    for (int r = 0; r < R_; r++) dtw[r] = dtw_all[((size_t)k * Dn + d) * R_ + r];
    f32x2 w2[6];
#pragma unroll
    for (int r = 0; r < 6; r++) w2[r] = mk2(dtw[2 * r], dtw[2 * r + 1]);
    const float bias = dtb_all[k * Dn + d];
    const float Dk = dvec[k * Dn + d];
    float Av[Nst];
    bool fast = true;
#pragma unroll
    for (int n = 0; n < Nst; n++) {
        Av[n] = -__expf(alog[((size_t)k * Dn + d) * Nst + n]);
        fast = fast && (fabsf(Av[n] + (float)(n + 1)) < 1e-3f);
    }

    size_t hbase = ((((size_t)(b * K_ + k) * NC + c) * Dn + d)) * Nst;
    const long stepD = (long)stride * Dn;
    const short* up = xcb + ((size_t)b * L_ + lm0) * Dn + d;
    short* yp = yk + ((size_t)b * L_ + lm0) * Dn + d;

    if (fast) {
        const float4* hi4 = reinterpret_cast<const float4*>(hin + hbase);
        float4 ha = hi4[0], hb = hi4[1];
        f32x2 h01 = lo2(ha), h23 = hi2(ha), h45 = lo2(hb), h67 = hi2(hb);
        for (int g = 0; g < CS / GS; ++g) {
            const short* ug = up + (long)g * GS * stepD;
            short* yg = yp + (long)g * GS * stepD;
            float e1a[GS], dua[GS], dku[GS];
            // loop A: independent chains
#pragma unroll
            for (int j = 0; j < GS; ++j) {
                int ts = g * GS + j;
                float u = bf2f(ug[(long)j * stepD]);
                float4 q0 = sx4[ts][0], q1 = sx4[ts][1], q2 = sx4[ts][2];
                float delta, e1; delta_e1(dot12p(q0, q1, q2, w2, bias), delta, e1);
                e1a[j] = e1;
                dua[j] = delta * u;
                dku[j] = Dk * u;
            }
            // loop B: serial h recurrence + y emission
#pragma unroll
            for (int j = 0; j < GS; ++j) {
                int ts = g * GS + j;
                float e1 = e1a[j], du = dua[j];
                float4 qb0 = sx4[ts][3], qb1 = sx4[ts][4];
                float4 qc0 = sx4[ts][5], qc1 = sx4[ts][6];
                float a2 = e1 * e1;
                f32x2 p12 = mk2(e1, a2);
                f32x2 a22 = mk2(a2, a2);
                f32x2 p34 = a22 * p12;
                f32x2 a44 = mk2(p34.y, p34.y);
                f32x2 p56 = a44 * p12;
                f32x2 p78 = a44 * p34;
                f32x2 du2 = mk2(du, du);
                h01 = pkfma(p12, h01, du2 * lo2(qb0));
                h23 = pkfma(p34, h23, du2 * hi2(qb0));
                h45 = pkfma(p56, h45, du2 * lo2(qb1));
                h67 = pkfma(p78, h67, du2 * hi2(qb1));
                f32x2 yacc = mk2(dku[j], 0.f);
                yacc = pkfma(h01, lo2(qc0), yacc);
                yacc = pkfma(h23, hi2(qc0), yacc);
                yacc = pkfma(h45, lo2(qc1), yacc);
                yacc = pkfma(h67, hi2(qc1), yacc);
                yg[(long)j * stepD] = f2bf(yacc.x + yacc.y);
            }
        }
    } else {
        float h[Nst];
#pragma unroll
        for (int n = 0; n < Nst; n++) h[n] = hin[hbase + n];
        float u_next = bf2f(*up);
        const short* upp = up;
        short* ypp = yp;
        for (int ts = 0; ts < CS; ts++) {
            float u = u_next;
            upp += stepD;
            if (ts + 1 < CS) u_next = bf2f(*upp);
            float4 q0 = sx4[ts][0], q1 = sx4[ts][1], q2 = sx4[ts][2];
            float4 qb0 = sx4[ts][3], qb1 = sx4[ts][4];
            float4 qc0 = sx4[ts][5], qc1 = sx4[ts][6];
            float Bv[Nst] = {qb0.x, qb0.y, qb0.z, qb0.w, qb1.x, qb1.y, qb1.z, qb1.w};
            float Cv[Nst] = {qc0.x, qc0.y, qc0.z, qc0.w, qc1.x, qc1.y, qc1.z, qc1.w};
            float delta, e1; delta_e1(dot12(q0, q1, q2, dtw, bias), delta, e1);
            float du = delta * u;
            float y = Dk * u;
#pragma unroll
            for (int n = 0; n < Nst; n++) {
                float a = __expf(delta * Av[n]);
                h[n] = fmaf(a, h[n], du * Bv[n]);
                y = fmaf(h[n], Cv[n], y);
            }
            *ypp = f2bf(y);
            ypp += stepD;
        }
    }
}

// ---------------- merge 4 dirs + LayerNorm(Dn) * SiLU(z) -> bf16 ------------
__global__ __launch_bounds__(256) void k_ln(const short* __restrict__ y0,
                                            const short* __restrict__ y1,
                                            const short* __restrict__ y2,
                                            const short* __restrict__ y3,
                                            const short* __restrict__ zb,
                                            const float* __restrict__ lnw,
                                            const float* __restrict__ lnb,
                                            short* __restrict__ yfin) {
    const int row = blockIdx.x * 4 + (threadIdx.x >> 6);
    const int lane = threadIdx.x & 63;
    const size_t base = (size_t)row * Dn;
    float v[3];
    float s = 0.f, s2 = 0.f;
#pragma unroll
    for (int j = 0; j < 3; j++) {
        size_t idx = base + lane + j * 64;
        v[j] = bf2f(y0[idx]) + bf2f(y1[idx]) + bf2f(y2[idx]) + bf2f(y3[idx]);
        s += v[j];
        s2 = fmaf(v[j], v[j], s2);
    }
#pragma unroll
    for (int o = 1; o < 64; o <<= 1) {
        s += __shfl_xor(s, o);
        s2 += __shfl_xor(s2, o);
    }
    const float inv = 1.f / 192.f;
    float mu = s * inv;
    float var = s2 * inv - mu * mu;
    float rstd = rsqrtf(var + 1e-5f);
#pragma unroll
    for (int j = 0; j < 3; j++) {
        int dd = lane + j * 64;
        size_t idx = base + dd;
        float zz = bf2f(zb[idx]);
        float sig = 1.f / (1.f + __expf(-zz));
        float res = ((v[j] - mu) * rstd * lnw[dd] + lnb[dd]) * (zz * sig);
        yfin[idx] = f2bf(res);
    }
}

// ---------------- launcher ---------------------------------------------------
extern "C" void kernel_launch(void* const* d_in, const int* in_sizes, int n_in,
                              void* d_out, int out_size, void* d_ws, size_t ws_size,
                              hipStream_t stream) {
    const float* x    = (const float*)d_in[0];
    const float* w_in = (const float*)d_in[1];
    const float* cw   = (const float*)d_in[2];
    const float* cb   = (const float*)d_in[3];
    const float* xpw  = (const float*)d_in[4];
    const float* dtw  = (const float*)d_in[5];
    const float* dtb  = (const float*)d_in[6];
    const float* alog = (const float*)d_in[7];
    const float* dvec = (const float*)d_in[8];
    const float* lnw  = (const float*)d_in[9];
    const float* lnb  = (const float*)d_in[10];
    const float* wout = (const float*)d_in[11];
    float* out = (float*)d_out;

    const size_t SH  = (size_t)MROWS * Dn;               // 6,291,456 elems
    const size_t SCN = (size_t)B_ * K_ * NC * Dn * Nst;  // 6,291,456 elems

    char* p = (char*)d_ws;
    short* x_bf  = (short*)p; p += SH * 2;               // region0 -> y0
    short* xf_bf = (short*)p; p += SH * 2;               // region1 -> y1
    short* z_bf  = (short*)p; p += SH * 2;               // region2
    short* xc_bf = (short*)p; p += SH * 2;               // region3
    float* xdbl  = (float*)p; p += (size_t)MROWS * (K_ * CPROJ) * 4;
    float* Aprod = (float*)p; p += SCN * 4;              // region5 -> y2
    float* hpart = (float*)p; p += SCN * 4;              // region6 -> y3
    float* hin   = (float*)p; p += SCN * 4;              // region7 -> yfin
    short* w_bf  = (short*)p;
    // aliases (lifetimes): y0<-x_bf (dead after in_proj), y1<-xf_bf (dead after
    // conv), y2<-Aprod, y3<-hpart (dead after scan2), yfin<-hin (dead after
    // scan3; k_ln runs after scan3).
    short* y0 = x_bf;
    short* y1 = xf_bf;
    short* y2 = (short*)Aprod;
    short* y3 = (short*)hpart;
    short* yfin_bf = (short*)hin;

    // 0. fused converts
    k_cvt<<<(XUNITS + WUNITS + 255) / 256, 256, 0, stream>>>(x, w_in, xpw, wout,
                                                             x_bf, w_bf);
    // 1. in_proj (MFMA) -> xf_bf, z_bf
    k_mgemm_in<<<dim3(MROWS / 128, 6), 256, 0, stream>>>(x_bf, w_bf + WOFF_IN,
                                                         xf_bf, z_bf, C_);
    // 2. depthwise conv 3x3 + SiLU -> xc_bf (8-row strip x 4 ch per thread)
    k_conv<<<B_ * (H_ / 8) * (W_ / 4), 192, 0, stream>>>(xf_bf, cw, cb, xc_bf);
    // 3. x_dbl (all 4 dirs, one MFMA GEMM) -> f32
    k_mgemm_f<<<dim3(MROWS / 128, 2), 256, 0, stream>>>(xc_bf, w_bf + WOFF_XP,
                                                        xdbl, K_ * CPROJ, Dn);
    // 4-6. chunked parallel selective scan (CS=32, software-pipelined groups)
    k_scan1<<<B_ * K_ * NC, 192, 0, stream>>>(xc_bf, xdbl, dtw, dtb, alog, Aprod, hpart);
    k_scan2<<<(B_ * K_ * Dn * Nst) / 256, 256, 0, stream>>>(Aprod, hpart, hin);
    k_scan3<<<B_ * K_ * NC, 192, 0, stream>>>(xc_bf, xdbl, dtw, dtb, alog, dvec,
                                              hin, y0, y1, y2, y3);
    // 7. merge + LayerNorm * SiLU(z) -> bf16
    k_ln<<<MROWS / 4, 256, 0, stream>>>(y0, y1, y2, y3, z_bf, lnw, lnb, yfin_bf);
    // 8. out_proj (MFMA) -> d_out (f32)
    k_mgemm_f<<<dim3(MROWS / 128, 3), 256, 0, stream>>>(yfin_bf, w_bf + WOFF_OUT,
                                                        out, C_, Dn);
}